// Round 8
// baseline (362.253 us; speedup 1.0000x reference)
//
#include <hip/hip_runtime.h>
#include <stdint.h>

// Problem constants (from reference): B,T,X,E,H,L = 4096,32,256,32,512,2
#define B_SZ 4096
#define T_SZ 32
#define X_SZ 256
#define E_SZ 32
#define H_SZ 512
#define BM   128     // batch rows per block

typedef __attribute__((ext_vector_type(8))) short  short8;   // 8 bf16 = 4 VGPR
typedef __attribute__((ext_vector_type(4))) float  floatx4;

// v_cvt_pk_bf16_f32: D[15:0]=bf16(a), D[31:16]=bf16(b), RNE (gfx950 HW instr)
__device__ __forceinline__ unsigned pk2(float a, float b) {
  unsigned r;
  asm("v_cvt_pk_bf16_f32 %0, %1, %2" : "=v"(r) : "v"(a), "v"(b));
  return r;
}

// ---------------------------------------------------------------------------
// Prep: fp32 weights -> bf16 MFMA B-fragments via LDS transpose. (unchanged)
// One block per chunk (32 k x 512 n). 1312 chunks total:
//   c in [0,288):    layer-1, c = e*9+kt. kt==0 -> masked W1t rows 0..31;
//                    kt>=1 -> W1x rows (kt-1)*32 .. +31.   out: wcat.
//   c in [288,1312): hidden, c-288 = (layer*32+e)*16 + kt. out: whf.
// Unit layout (contract with mlp_kernel): u = nb*64 + l,
//   n = nb*16 + (l&15), local k0 = (l>>4)*8, dword p covers k = k0+2p, k0+2p+1.
// ---------------------------------------------------------------------------
__global__ __launch_bounds__(256) void prep_kernel(
    const float* __restrict__ W1t, const float* __restrict__ W1x,
    const int* __restrict__ masks, const float* __restrict__ Wh,
    uint4* __restrict__ wcat, uint4* __restrict__ whf) {
  __shared__ unsigned lds[16 * 516];           // 33 KB
  const int c = blockIdx.x;
  const int t = threadIdx.x;

  const float* base;                           // row 0 of this chunk's 32 rows
  bool needMask = false;
  int e1 = 0;
  if (c >= 288) {
    int cc = c - 288;
    int le = cc >> 4, kt = cc & 15;            // le = layer*32 + e
    base = Wh + ((size_t)le * H_SZ + kt * 32) * H_SZ;
  } else {
    int e = c / 9, kt = c - e * 9;
    e1 = e;
    if (kt == 0) { base = W1t + (size_t)e * T_SZ * H_SZ; needMask = true; }
    else          base = W1x + ((size_t)e * X_SZ + (kt - 1) * 32) * H_SZ;
  }

#pragma unroll
  for (int i = 0; i < 8; ++i) {
    int g  = i * 256 + t;
    int k2 = g >> 7, np = g & 127;             // k2: wave-uniform
    const float* r0 = base + (size_t)(2 * k2) * H_SZ + np * 4;
    float4 a = *(const float4*)r0;
    float4 b = *(const float4*)(r0 + H_SZ);
    if (needMask) {
      float s0 = (float)masks[e1 * T_SZ + 2 * k2];
      float s1 = (float)masks[e1 * T_SZ + 2 * k2 + 1];
      a.x *= s0; a.y *= s0; a.z *= s0; a.w *= s0;
      b.x *= s1; b.y *= s1; b.z *= s1; b.w *= s1;
    }
    *(uint4*)&lds[k2 * 516 + np * 4] =
        make_uint4(pk2(a.x, b.x), pk2(a.y, b.y), pk2(a.z, b.z), pk2(a.w, b.w));
  }
  __syncthreads();

  uint4* outp = (c < 288) ? (wcat + (size_t)c * 2048)
                          : (whf + (size_t)(c - 288) * 2048);
  const int w = t >> 6, l = t & 63, q = l >> 4, l16 = l & 15;
#pragma unroll
  for (int j = 0; j < 8; ++j) {
    int nb = w * 8 + j;
    int n  = nb * 16 + l16;
    int kb = 4 * q;
    uint4 v;
    v.x = lds[(kb + 0) * 516 + n];
    v.y = lds[(kb + 1) * 516 + n];
    v.z = lds[(kb + 2) * 516 + n];
    v.w = lds[(kb + 3) * 516 + n];
    outp[nb * 64 + l] = v;                     // 16B/lane, lanes consecutive
  }
}

// ---------------------------------------------------------------------------
// Fused MLP v8: BM=128, 1024 threads (16 waves), 1 block/CU, 4 waves/SIMD.
// Wave w: row-half rh=w&1, col-strip wc=w>>1 (64x64 output, acc[4][4]).
// vs v6 (213us, MfmaUtil 37%): TRUE 2-CHUNK-DEEP B PREFETCH. v6 issued B
// loads only ~350cy before use, but the per-CU weight burst (64KB/chunk)
// drains the L1 fill path in ~1000cy -> synchronized vmcnt stalls. Fix:
// i-outer/m-inner MFMA order (FP-identical; each acc[m][i] gets exactly one
// MFMA per chunk) so b[i] dies after its 4 MFMAs, then reload IN PLACE with
// chunk k+2's fragment: issue->use = 2 chunks (~1500cy >> drain), constant
// counted vmcnt. Registers: af16+bcur16+bnxt16+acc64+misc ~ 125 <= 128 cap.
// A-frag reads stay v6-style (fresh per chunk section; v7's interleaved
// lgkm reload REGRESSED - do not reintroduce).
// A buffer FRAGMENT-MAJOR, (mb,kt) order: unit(mb,kt,lane) at
// (mb*16384 + kt*1024 + lane*16).
// Block map: all 32 CUs of an XCD run the same expert concurrently.
// ---------------------------------------------------------------------------
__global__ __launch_bounds__(1024, 4) void mlp_kernel(
    const float* __restrict__ theta, const float* __restrict__ x,
    const short8* __restrict__ wcat, const short8* __restrict__ whf,
    const float* __restrict__ b1, const float* __restrict__ a1,
    const float* __restrict__ bh, const float* __restrict__ ah,
    const float* __restrict__ Wo, const float* __restrict__ bo,
    float* __restrict__ out) {
  __shared__ __align__(16) char smA[8 * 16 * 64 * 16];   // 131072 B, 1 block/CU
  const int tid = threadIdx.x;
  const int bid = blockIdx.x;
  const int xcd = bid & 7;
  const int t8  = bid >> 3;                       // per-XCD sequence 0..127
  const int e   = xcd * 4 + (t8 >> 5);            // 32 consecutive blocks/expert
  const int m0  = (t8 & 31) * BM;
  const int w   = tid >> 6, l = tid & 63, l16 = l & 15, quad = l >> 4;
  const int rh  = w & 1;                          // row half (0: rows 0-63)
  const int wc  = w >> 1;                         // col strip (64 cols)

  // ---- stage A0 = [theta | x] bf16, directly in fragment order ----
  // g: lane=g&63, mb=(g>>6)&7, kt=g>>9; row = mb*16+(lane&15),
  // k = kt*32 + (lane>>4)*8 .. +7  (kt==0 -> theta cols, else x cols).
  for (int g = tid; g < 9 * 512; g += 1024) {
    int lane = g & 63, mb = (g >> 6) & 7, kt = g >> 9;
    int row  = m0 + mb * 16 + (lane & 15);
    int ks   = (lane >> 4) * 8;
    const float* src = (kt == 0)
                           ? (theta + (size_t)row * T_SZ + ks)
                           : (x + (size_t)row * X_SZ + (kt - 1) * 32 + ks);
    float4 a = *(const float4*)src;
    float4 b = *(const float4*)(src + 4);
    *(uint4*)(smA + mb * 16384 + kt * 1024 + lane * 16) =
        make_uint4(pk2(a.x, a.y), pk2(a.z, a.w), pk2(b.x, b.y), pk2(b.z, b.w));
  }
  __syncthreads();

  floatx4 acc[4][4];
  const int u0 = wc * 256 + l;                    // weight unit index (nb=wc*4)
  const char* dsb0 = smA + rh * 65536 + l * 16;   // A-frag base (chunk 0)

  // GEMM over nkt K-chunks of 32 (nkt >= 2 always). Runtime loop, 2 chunks
  // per iter; B-fragments rolled in place 2 chunks ahead of use.
  auto gemm = [&](const short8* wbase, int nkt) {
#pragma unroll
    for (int m = 0; m < 4; ++m)
#pragma unroll
      for (int i = 0; i < 4; ++i) acc[m][i] = (floatx4)(0.f);
    short8 af[4], bcur[4], bnxt[4];
    const short8* wu = wbase;                     // uniform -> SGPR base
#pragma unroll
    for (int i = 0; i < 4; ++i) bcur[i] = wu[u0 + i * 64];          // chunk 0
#pragma unroll
    for (int i = 0; i < 4; ++i) bnxt[i] = wu[2048 + u0 + i * 64];   // chunk 1
    const char* dsb = dsb0;
    const int half = nkt >> 1;
#pragma unroll 1
    for (int j = 0; j < half; ++j) {
      // ---- chunk 2j (B in bcur) ----
#pragma unroll
      for (int m = 0; m < 4; ++m)
        af[m] = *(const short8*)(dsb + m * 16384);
      const short8* w2 = (2 * j + 2 < nkt) ? wu + 4096 : wu;  // clamp: dummy
#pragma unroll
      for (int i = 0; i < 4; ++i) {
#pragma unroll
        for (int m = 0; m < 4; ++m)
          acc[m][i] = __builtin_amdgcn_mfma_f32_16x16x32_bf16(
              af[m], bcur[i], acc[m][i], 0, 0, 0);
        bcur[i] = w2[u0 + i * 64];                // roll: chunk 2j+2 in flight
      }
      // ---- chunk 2j+1 (B in bnxt) ----
#pragma unroll
      for (int m = 0; m < 4; ++m)
        af[m] = *(const short8*)(dsb + m * 16384 + 1024);
      const short8* w3 = (2 * j + 3 < nkt) ? wu + 6144 : wu;  // clamp: dummy
#pragma unroll
      for (int i = 0; i < 4; ++i) {
#pragma unroll
        for (int m = 0; m < 4; ++m)
          acc[m][i] = __builtin_amdgcn_mfma_f32_16x16x32_bf16(
              af[m], bnxt[i], acc[m][i], 0, 0, 0);
        bnxt[i] = w3[u0 + i * 64];                // roll: chunk 2j+3 in flight
      }
      wu += 4096;
      dsb += 2048;
    }
    if (nkt & 1) {   // tail chunk nkt-1 (even idx): loaded into bcur by j=half-1
#pragma unroll
      for (int m = 0; m < 4; ++m)
        af[m] = *(const short8*)(dsb + m * 16384);
#pragma unroll
      for (int i = 0; i < 4; ++i)
#pragma unroll
        for (int m = 0; m < 4; ++m)
          acc[m][i] = __builtin_amdgcn_mfma_f32_16x16x32_bf16(
              af[m], bcur[i], acc[m][i], 0, 0, 0);
    }
  };

  // bias + PReLU + bf16 pair-pack (shfl_xor 1) + write into fragment-major A.
  // Value (R = rh*64+mb*16+quad*4+r, C = wc*64+i*16+l16) -> unit
  // mb' = rh*4+mb, kt' = wc*2+(i>>1), lane' = (R&15) + ((i*2+(l16>>3))&3)*16,
  // byte-in-lane (l16&6)*2.
  auto epi_store = [&](const float* bias, const float* slope) {
    float bb[4], aa[4];
#pragma unroll
    for (int i = 0; i < 4; ++i) {
      int col = wc * 64 + i * 16 + l16;
      bb[i] = bias[col];
      aa[i] = slope[col];
    }
    __syncthreads();   // everyone done READING A before we overwrite
#pragma unroll
    for (int mb = 0; mb < 4; ++mb) {
#pragma unroll
      for (int i = 0; i < 4; ++i) {
        unsigned dw[4];
#pragma unroll
        for (int r = 0; r < 4; ++r) {
          float v = acc[mb][i][r] + bb[i];
          v = v >= 0.f ? v : aa[i] * v;
          float o  = __shfl_xor(v, 1, 64);
          float lo = (l16 & 1) ? o : v;
          float hi = (l16 & 1) ? v : o;
          dw[r] = pk2(lo, hi);
        }
        int rbase = (l16 & 1) * 2;               // even lanes rows 0,1; odd 2,3
        int mbp   = rh * 4 + mb;
        int ktp   = wc * 2 + (i >> 1);
        int lhi   = ((i * 2 + (l16 >> 3)) & 3) * 16;
        char* ubase = smA + mbp * 16384 + ktp * 1024 + (l16 & 6) * 2;
#pragma unroll
        for (int rr = 0; rr < 2; ++rr) {
          int lane_p = (quad * 4 + rbase + rr) + lhi;
          *(unsigned*)(ubase + lane_p * 16) = dw[rbase + rr];
        }
      }
    }
    __syncthreads();
  };

  // ---- layer 1: K = 288 (9 chunks) ----
  gemm(wcat + (size_t)e * 9 * 2048, 9);
  epi_store(b1 + (size_t)e * H_SZ, a1 + (size_t)e * H_SZ);
  // ---- hidden layer 0: K = 512 (16 chunks) ----
  gemm(whf + (size_t)e * 16 * 2048, 16);
  epi_store(bh + (size_t)e * H_SZ, ah + (size_t)e * H_SZ);
  // ---- hidden layer 1 + fused output dot (fp32, no bf16 rounding) ----
  gemm(whf + (size_t)(E_SZ + e) * 16 * 2048, 16);
  {
    float bb[4], aa[4], wo[4];
#pragma unroll
    for (int i = 0; i < 4; ++i) {
      int col = wc * 64 + i * 16 + l16;
      bb[i] = bh[(size_t)(E_SZ + e) * H_SZ + col];
      aa[i] = ah[(size_t)(E_SZ + e) * H_SZ + col];
      wo[i] = Wo[(size_t)e * H_SZ + col];
    }
    float ps[4][4];
#pragma unroll
    for (int m = 0; m < 4; ++m)
#pragma unroll
      for (int r = 0; r < 4; ++r) ps[m][r] = 0.f;
#pragma unroll
    for (int m = 0; m < 4; ++m)
#pragma unroll
      for (int i = 0; i < 4; ++i)
#pragma unroll
        for (int r = 0; r < 4; ++r) {
          float v = acc[m][i][r] + bb[i];
          v = v >= 0.f ? v : aa[i] * v;
          ps[m][r] += v * wo[i];
        }
    // reduce over the 16 lanes of each quad (cols within this wave's strip)
#pragma unroll
    for (int d = 1; d < 16; d <<= 1)
#pragma unroll
      for (int m = 0; m < 4; ++m)
#pragma unroll
        for (int r = 0; r < 4; ++r) ps[m][r] += __shfl_xor(ps[m][r], d, 64);
    __syncthreads();                 // done reading A; reuse its storage
    float* scratch = (float*)smA;    // [128 rows][8 col-strips]
    if (l16 == 0) {
#pragma unroll
      for (int m = 0; m < 4; ++m)
#pragma unroll
        for (int r = 0; r < 4; ++r)
          scratch[(rh * 64 + m * 16 + quad * 4 + r) * 8 + wc] = ps[m][r];
    }
    __syncthreads();
    if (tid < BM) {
      float s = 0.f;
#pragma unroll
      for (int ww = 0; ww < 8; ++ww) s += scratch[tid * 8 + ww];
      out[(size_t)(m0 + tid) * E_SZ + e] = s + bo[e];
    }
  }
}

// ---------------------------------------------------------------------------
extern "C" void kernel_launch(void* const* d_in, const int* in_sizes, int n_in,
                              void* d_out, int out_size, void* d_ws, size_t ws_size,
                              hipStream_t stream) {
  const float* theta = (const float*)d_in[0];
  const float* x     = (const float*)d_in[1];
  const int*   masks = (const int*)d_in[2];
  const float* W1t   = (const float*)d_in[3];
  const float* W1x   = (const float*)d_in[4];
  const float* b1    = (const float*)d_in[5];
  const float* a1    = (const float*)d_in[6];
  const float* Wh    = (const float*)d_in[7];
  const float* bh    = (const float*)d_in[8];
  const float* ah    = (const float*)d_in[9];
  const float* Wo    = (const float*)d_in[10];
  const float* bo    = (const float*)d_in[11];
  float* out = (float*)d_out;

  // ws layout: [0, 9.4MB) layer-1 frags; [9.4MB, 43MB) hidden frags.
  uint4* wcat = (uint4*)d_ws;
  uint4* whf  = (uint4*)((char*)d_ws + (size_t)E_SZ * 9 * 2048 * 16);

  // 288 layer-1 chunks + 1024 hidden chunks, one block each
  prep_kernel<<<1312, 256, 0, stream>>>(W1t, W1x, masks, Wh, wcat, whf);
  // 1024 blocks: 32 m-tiles x 32 experts, 1024 threads each
  mlp_kernel<<<1024, 1024, 0, stream>>>(theta, x, (const short8*)wcat,
                                        (const short8*)whf, b1, a1, bh, ah, Wo,
                                        bo, out);
}

// Round 10
// 307.158 us; speedup vs baseline: 1.1794x; 1.1794x over previous
//
#include <hip/hip_runtime.h>
#include <stdint.h>

// Problem constants (from reference): B,T,X,E,H,L = 4096,32,256,32,512,2
#define B_SZ 4096
#define T_SZ 32
#define X_SZ 256
#define E_SZ 32
#define H_SZ 512
#define BM   64      // batch rows per block; 2 blocks/CU (independent phases)

typedef __attribute__((ext_vector_type(8))) short  short8;   // 8 bf16 = 4 VGPR
typedef __attribute__((ext_vector_type(4))) float  floatx4;

// v_cvt_pk_bf16_f32: D[15:0]=bf16(a), D[31:16]=bf16(b), RNE (gfx950 HW instr)
__device__ __forceinline__ unsigned pk2(float a, float b) {
  unsigned r;
  asm("v_cvt_pk_bf16_f32 %0, %1, %2" : "=v"(r) : "v"(a), "v"(b));
  return r;
}

// ---------------------------------------------------------------------------
// Prep: fp32 weights -> bf16 MFMA B-fragments via LDS transpose. (unchanged)
// One block per chunk (32 k x 512 n). 1312 chunks total:
//   c in [0,288):    layer-1, c = e*9+kt. kt==0 -> masked W1t rows 0..31;
//                    kt>=1 -> W1x rows (kt-1)*32 .. +31.   out: wcat.
//   c in [288,1312): hidden, c-288 = (layer*32+e)*16 + kt. out: whf.
// Unit layout (contract with mlp_kernel): u = nb*64 + l,
//   n = nb*16 + (l&15), local k0 = (l>>4)*8, dword p covers k = k0+2p, k0+2p+1.
// ---------------------------------------------------------------------------
__global__ __launch_bounds__(256) void prep_kernel(
    const float* __restrict__ W1t, const float* __restrict__ W1x,
    const int* __restrict__ masks, const float* __restrict__ Wh,
    uint4* __restrict__ wcat, uint4* __restrict__ whf) {
  __shared__ unsigned lds[16 * 516];           // 33 KB
  const int c = blockIdx.x;
  const int t = threadIdx.x;

  const float* base;                           // row 0 of this chunk's 32 rows
  bool needMask = false;
  int e1 = 0;
  if (c >= 288) {
    int cc = c - 288;
    int le = cc >> 4, kt = cc & 15;            // le = layer*32 + e
    base = Wh + ((size_t)le * H_SZ + kt * 32) * H_SZ;
  } else {
    int e = c / 9, kt = c - e * 9;
    e1 = e;
    if (kt == 0) { base = W1t + (size_t)e * T_SZ * H_SZ; needMask = true; }
    else          base = W1x + ((size_t)e * X_SZ + (kt - 1) * 32) * H_SZ;
  }

#pragma unroll
  for (int i = 0; i < 8; ++i) {
    int g  = i * 256 + t;
    int k2 = g >> 7, np = g & 127;             // k2: wave-uniform
    const float* r0 = base + (size_t)(2 * k2) * H_SZ + np * 4;
    float4 a = *(const float4*)r0;
    float4 b = *(const float4*)(r0 + H_SZ);
    if (needMask) {
      float s0 = (float)masks[e1 * T_SZ + 2 * k2];
      float s1 = (float)masks[e1 * T_SZ + 2 * k2 + 1];
      a.x *= s0; a.y *= s0; a.z *= s0; a.w *= s0;
      b.x *= s1; b.y *= s1; b.z *= s1; b.w *= s1;
    }
    *(uint4*)&lds[k2 * 516 + np * 4] =
        make_uint4(pk2(a.x, b.x), pk2(a.y, b.y), pk2(a.z, b.z), pk2(a.w, b.w));
  }
  __syncthreads();

  uint4* outp = (c < 288) ? (wcat + (size_t)c * 2048)
                          : (whf + (size_t)(c - 288) * 2048);
  const int w = t >> 6, l = t & 63, q = l >> 4, l16 = l & 15;
#pragma unroll
  for (int j = 0; j < 8; ++j) {
    int nb = w * 8 + j;
    int n  = nb * 16 + l16;
    int kb = 4 * q;
    uint4 v;
    v.x = lds[(kb + 0) * 516 + n];
    v.y = lds[(kb + 1) * 516 + n];
    v.z = lds[(kb + 2) * 516 + n];
    v.w = lds[(kb + 3) * 516 + n];
    outp[nb * 64 + l] = v;                     // 16B/lane, lanes consecutive
  }
}

// ---------------------------------------------------------------------------
// Fused MLP v9 = session-best recombination:
//   * R0 structure (best measured, 197.8us): BM=64, 512 threads (8 waves),
//     64KB LDS -> TWO INDEPENDENT blocks/CU (phase diversity feeds the MFMA
//     pipe while the other block stalls on loads; every 1-block/CU variant
//     measured worse). Wave w owns cols [64w,64w+64) x all 64 rows, acc[4][4].
//   * Fragment-major A buffer (validated: conflicts 12.9M->2.6M):
//     unit(mb,kt,lane) at mb*16384 + kt*1024 + lane*16 holds
//     A[m0+mb*16+(lane&15)][kt*32+(lane>>4)*8 ..+7]; gemm ds_read_b128 = 64
//     consecutive lanes x 16B, conflict-free.
//   * v6's copy-free 2-chunk role-swap B double-buffer. NO in-place register
//     rolls, NO af interleave (v7/v8 both regressed: compiler's schedule of
//     the plain form is the optimum).
//   * T5 s_setprio(1) around MFMA clusters: pays in multi-phase regimes
//     (independent blocks), per guide m191.
//   * R0 block map: e=(r5&7)*4+(r5>>3) (XCD-local experts), m0=(bid>>5)*64;
//     co-resident blocks (bid, bid+256) share the expert -> L1/L2 weight hits.
// ---------------------------------------------------------------------------
__global__ __launch_bounds__(512, 4) void mlp_kernel(
    const float* __restrict__ theta, const float* __restrict__ x,
    const short8* __restrict__ wcat, const short8* __restrict__ whf,
    const float* __restrict__ b1, const float* __restrict__ a1,
    const float* __restrict__ bh, const float* __restrict__ ah,
    const float* __restrict__ Wo, const float* __restrict__ bo,
    float* __restrict__ out) {
  __shared__ __align__(16) char smA[4 * 16 * 64 * 16];   // 65536 B
  const int tid = threadIdx.x;
  const int bid = blockIdx.x;
  const int r5  = bid & 31;
  const int e   = (r5 & 7) * 4 + (r5 >> 3);       // same-expert blocks -> same XCD
  const int m0  = (bid >> 5) * BM;
  const int w   = tid >> 6, l = tid & 63, l16 = l & 15, quad = l >> 4;

  // ---- stage A0 = [theta | x] bf16, directly in fragment order ----
  // g: lane=g&63, mb=(g>>6)&3, kt=g>>8; row = mb*16+(lane&15),
  // k = kt*32 + (lane>>4)*8 .. +7  (kt==0 -> theta cols, else x cols).
  for (int g = tid; g < 9 * 256; g += 512) {
    int lane = g & 63, mb = (g >> 6) & 3, kt = g >> 8;
    int row  = m0 + mb * 16 + (lane & 15);
    int ks   = (lane >> 4) * 8;
    const float* src = (kt == 0)
                           ? (theta + (size_t)row * T_SZ + ks)
                           : (x + (size_t)row * X_SZ + (kt - 1) * 32 + ks);
    float4 a = *(const float4*)src;
    float4 b = *(const float4*)(src + 4);
    *(uint4*)(smA + mb * 16384 + kt * 1024 + lane * 16) =
        make_uint4(pk2(a.x, a.y), pk2(a.z, a.w), pk2(b.x, b.y), pk2(b.z, b.w));
  }
  __syncthreads();

  floatx4 acc[4][4];
  const int u0 = w * 256 + l;                     // weight unit index (nb=4w)
  const char* dsb0 = smA + l * 16;                // A-frag base (chunk 0)

  // GEMM over nkt K-chunks of 32. Runtime loop, 2 chunks/iter, bA/bB role
  // swap (no copies); af read fresh per chunk (plain form - fastest measured).
  auto gemm = [&](const short8* wbase, int nkt) {
#pragma unroll
    for (int m = 0; m < 4; ++m)
#pragma unroll
      for (int i = 0; i < 4; ++i) acc[m][i] = (floatx4)(0.f);
    short8 bA[4], bB[4];
    const short8* wu = wbase;                     // uniform -> SGPR base
#pragma unroll
    for (int i = 0; i < 4; ++i) bA[i] = wu[u0 + i * 64];   // chunk 0
    const char* dsb = dsb0;
    const int half = nkt >> 1;
#pragma unroll 1
    for (int j = 0; j < half; ++j) {
      // prefetch odd chunk 2j+1 (always valid inside loop)
      const short8* w1 = wu + 2048;
#pragma unroll
      for (int i = 0; i < 4; ++i) bB[i] = w1[u0 + i * 64];
      // chunk 2j with bA
      {
        short8 af[4];
#pragma unroll
        for (int m = 0; m < 4; ++m)
          af[m] = *(const short8*)(dsb + m * 16384);
        __builtin_amdgcn_s_setprio(1);
#pragma unroll
        for (int m = 0; m < 4; ++m)
#pragma unroll
          for (int i = 0; i < 4; ++i)
            acc[m][i] = __builtin_amdgcn_mfma_f32_16x16x32_bf16(
                af[m], bA[i], acc[m][i], 0, 0, 0);
        __builtin_amdgcn_s_setprio(0);
      }
      // prefetch chunk 2j+2 (clamped at layer end; uniform select -> SALU)
      const short8* w2 = (2 * j + 2 < nkt) ? wu + 4096 : wu;
#pragma unroll
      for (int i = 0; i < 4; ++i) bA[i] = w2[u0 + i * 64];
      // chunk 2j+1 with bB
      {
        short8 af[4];
#pragma unroll
        for (int m = 0; m < 4; ++m)
          af[m] = *(const short8*)(dsb + m * 16384 + 1024);
        __builtin_amdgcn_s_setprio(1);
#pragma unroll
        for (int m = 0; m < 4; ++m)
#pragma unroll
          for (int i = 0; i < 4; ++i)
            acc[m][i] = __builtin_amdgcn_mfma_f32_16x16x32_bf16(
                af[m], bB[i], acc[m][i], 0, 0, 0);
        __builtin_amdgcn_s_setprio(0);
      }
      wu += 4096;
      dsb += 2048;
    }
    if (nkt & 1) {                                // tail chunk nkt-1 (in bA)
      short8 af[4];
#pragma unroll
      for (int m = 0; m < 4; ++m)
        af[m] = *(const short8*)(dsb + m * 16384);
      __builtin_amdgcn_s_setprio(1);
#pragma unroll
      for (int m = 0; m < 4; ++m)
#pragma unroll
        for (int i = 0; i < 4; ++i)
          acc[m][i] = __builtin_amdgcn_mfma_f32_16x16x32_bf16(
              af[m], bA[i], acc[m][i], 0, 0, 0);
      __builtin_amdgcn_s_setprio(0);
    }
  };

  // bias + PReLU + bf16 pair-pack (shfl_xor 1) + write into fragment-major A.
  // Value (R = mb*16+quad*4+r, C = w*64+i*16+l16) -> unit mb'=mb,
  // kt' = w*2+(i>>1), lane' = (R&15) + ((i*2+(l16>>3))&3)*16,
  // byte-in-lane (l16&6)*2.
  auto epi_store = [&](const float* bias, const float* slope) {
    float bb[4], aa[4];
#pragma unroll
    for (int i = 0; i < 4; ++i) {
      int col = w * 64 + i * 16 + l16;
      bb[i] = bias[col];
      aa[i] = slope[col];
    }
    __syncthreads();   // everyone done READING A before we overwrite
#pragma unroll
    for (int mb = 0; mb < 4; ++mb) {
#pragma unroll
      for (int i = 0; i < 4; ++i) {
        unsigned dw[4];
#pragma unroll
        for (int r = 0; r < 4; ++r) {
          float v = acc[mb][i][r] + bb[i];
          v = v >= 0.f ? v : aa[i] * v;
          float o  = __shfl_xor(v, 1, 64);
          float lo = (l16 & 1) ? o : v;
          float hi = (l16 & 1) ? v : o;
          dw[r] = pk2(lo, hi);
        }
        int rbase = (l16 & 1) * 2;               // even lanes rows 0,1; odd 2,3
        int ktp   = w * 2 + (i >> 1);
        int lhi   = ((i * 2 + (l16 >> 3)) & 3) * 16;
        char* ubase = smA + mb * 16384 + ktp * 1024 + (l16 & 6) * 2;
#pragma unroll
        for (int rr = 0; rr < 2; ++rr) {
          int lane_p = (quad * 4 + rbase + rr) + lhi;
          *(unsigned*)(ubase + lane_p * 16) = dw[rbase + rr];
        }
      }
    }
    __syncthreads();
  };

  // ---- layer 1: K = 288 (9 chunks) ----
  gemm(wcat + (size_t)e * 9 * 2048, 9);
  epi_store(b1 + (size_t)e * H_SZ, a1 + (size_t)e * H_SZ);
  // ---- hidden layer 0: K = 512 (16 chunks) ----
  gemm(whf + (size_t)e * 16 * 2048, 16);
  epi_store(bh + (size_t)e * H_SZ, ah + (size_t)e * H_SZ);
  // ---- hidden layer 1 + fused output dot (fp32, no bf16 rounding) ----
  gemm(whf + (size_t)(E_SZ + e) * 16 * 2048, 16);
  {
    float bb[4], aa[4], wo[4];
#pragma unroll
    for (int i = 0; i < 4; ++i) {
      int col = w * 64 + i * 16 + l16;
      bb[i] = bh[(size_t)(E_SZ + e) * H_SZ + col];
      aa[i] = ah[(size_t)(E_SZ + e) * H_SZ + col];
      wo[i] = Wo[(size_t)e * H_SZ + col];
    }
    float ps[4][4];
#pragma unroll
    for (int m = 0; m < 4; ++m)
#pragma unroll
      for (int r = 0; r < 4; ++r) ps[m][r] = 0.f;
#pragma unroll
    for (int m = 0; m < 4; ++m)
#pragma unroll
      for (int i = 0; i < 4; ++i)
#pragma unroll
        for (int r = 0; r < 4; ++r) {
          float v = acc[m][i][r] + bb[i];
          v = v >= 0.f ? v : aa[i] * v;
          ps[m][r] += v * wo[i];
        }
    // reduce over the 16 lanes of each quad (cols within this wave's strip)
#pragma unroll
    for (int d = 1; d < 16; d <<= 1)
#pragma unroll
      for (int m = 0; m < 4; ++m)
#pragma unroll
        for (int r = 0; r < 4; ++r) ps[m][r] += __shfl_xor(ps[m][r], d, 64);
    __syncthreads();                 // done reading A; reuse its storage
    float* scratch = (float*)smA;    // [64 rows][8 col-strips]
    if (l16 == 0) {
#pragma unroll
      for (int m = 0; m < 4; ++m)
#pragma unroll
        for (int r = 0; r < 4; ++r)
          scratch[(m * 16 + quad * 4 + r) * 8 + w] = ps[m][r];
    }
    __syncthreads();
    if (tid < BM) {
      float s = 0.f;
#pragma unroll
      for (int ww = 0; ww < 8; ++ww) s += scratch[tid * 8 + ww];
      out[(size_t)(m0 + tid) * E_SZ + e] = s + bo[e];
    }
  }
}

// ---------------------------------------------------------------------------
extern "C" void kernel_launch(void* const* d_in, const int* in_sizes, int n_in,
                              void* d_out, int out_size, void* d_ws, size_t ws_size,
                              hipStream_t stream) {
  const float* theta = (const float*)d_in[0];
  const float* x     = (const float*)d_in[1];
  const int*   masks = (const int*)d_in[2];
  const float* W1t   = (const float*)d_in[3];
  const float* W1x   = (const float*)d_in[4];
  const float* b1    = (const float*)d_in[5];
  const float* a1    = (const float*)d_in[6];
  const float* Wh    = (const float*)d_in[7];
  const float* bh    = (const float*)d_in[8];
  const float* ah    = (const float*)d_in[9];
  const float* Wo    = (const float*)d_in[10];
  const float* bo    = (const float*)d_in[11];
  float* out = (float*)d_out;

  // ws layout: [0, 9.4MB) layer-1 frags; [9.4MB, 43MB) hidden frags.
  uint4* wcat = (uint4*)d_ws;
  uint4* whf  = (uint4*)((char*)d_ws + (size_t)E_SZ * 9 * 2048 * 16);

  // 288 layer-1 chunks + 1024 hidden chunks, one block each
  prep_kernel<<<1312, 256, 0, stream>>>(W1t, W1x, masks, Wh, wcat, whf);
  // 2048 blocks: 64 m-tiles x 32 experts, 512 threads, 2 blocks/CU
  mlp_kernel<<<2048, 512, 0, stream>>>(theta, x, (const short8*)wcat,
                                       (const short8*)whf, b1, a1, bh, ah, Wo,
                                       bo, out);
}

// Round 12
// 305.050 us; speedup vs baseline: 1.1875x; 1.0069x over previous
//
#include <hip/hip_runtime.h>
#include <stdint.h>

// Problem constants (from reference): B,T,X,E,H,L = 4096,32,256,32,512,2
#define B_SZ 4096
#define T_SZ 32
#define X_SZ 256
#define E_SZ 32
#define H_SZ 512
#define BM   64      // batch rows per block; 2 blocks/CU (independent phases)

typedef __attribute__((ext_vector_type(8))) short  short8;   // 8 bf16 = 4 VGPR
typedef __attribute__((ext_vector_type(4))) float  floatx4;

// v_cvt_pk_bf16_f32: D[15:0]=bf16(a), D[31:16]=bf16(b), RNE (gfx950 HW instr)
__device__ __forceinline__ unsigned pk2(float a, float b) {
  unsigned r;
  asm("v_cvt_pk_bf16_f32 %0, %1, %2" : "=v"(r) : "v"(a), "v"(b));
  return r;
}

// ---------------------------------------------------------------------------
// Prep: fp32 weights -> bf16 MFMA B-fragments via LDS transpose. (unchanged)
// One block per chunk (32 k x 512 n). 1312 chunks total:
//   c in [0,288):    layer-1, c = e*9+kt. kt==0 -> masked W1t rows 0..31;
//                    kt>=1 -> W1x rows (kt-1)*32 .. +31.   out: wcat.
//   c in [288,1312): hidden, c-288 = (layer*32+e)*16 + kt. out: whf.
// Unit layout (contract with mlp_kernel): u = nb*64 + l,
//   n = nb*16 + (l&15), local k0 = (l>>4)*8, dword p covers k = k0+2p, k0+2p+1.
// ---------------------------------------------------------------------------
__global__ __launch_bounds__(256) void prep_kernel(
    const float* __restrict__ W1t, const float* __restrict__ W1x,
    const int* __restrict__ masks, const float* __restrict__ Wh,
    uint4* __restrict__ wcat, uint4* __restrict__ whf) {
  __shared__ unsigned lds[16 * 516];           // 33 KB
  const int c = blockIdx.x;
  const int t = threadIdx.x;

  const float* base;                           // row 0 of this chunk's 32 rows
  bool needMask = false;
  int e1 = 0;
  if (c >= 288) {
    int cc = c - 288;
    int le = cc >> 4, kt = cc & 15;            // le = layer*32 + e
    base = Wh + ((size_t)le * H_SZ + kt * 32) * H_SZ;
  } else {
    int e = c / 9, kt = c - e * 9;
    e1 = e;
    if (kt == 0) { base = W1t + (size_t)e * T_SZ * H_SZ; needMask = true; }
    else          base = W1x + ((size_t)e * X_SZ + (kt - 1) * 32) * H_SZ;
  }

#pragma unroll
  for (int i = 0; i < 8; ++i) {
    int g  = i * 256 + t;
    int k2 = g >> 7, np = g & 127;             // k2: wave-uniform
    const float* r0 = base + (size_t)(2 * k2) * H_SZ + np * 4;
    float4 a = *(const float4*)r0;
    float4 b = *(const float4*)(r0 + H_SZ);
    if (needMask) {
      float s0 = (float)masks[e1 * T_SZ + 2 * k2];
      float s1 = (float)masks[e1 * T_SZ + 2 * k2 + 1];
      a.x *= s0; a.y *= s0; a.z *= s0; a.w *= s0;
      b.x *= s1; b.y *= s1; b.z *= s1; b.w *= s1;
    }
    *(uint4*)&lds[k2 * 516 + np * 4] =
        make_uint4(pk2(a.x, b.x), pk2(a.y, b.y), pk2(a.z, b.z), pk2(a.w, b.w));
  }
  __syncthreads();

  uint4* outp = (c < 288) ? (wcat + (size_t)c * 2048)
                          : (whf + (size_t)(c - 288) * 2048);
  const int w = t >> 6, l = t & 63, q = l >> 4, l16 = l & 15;
#pragma unroll
  for (int j = 0; j < 8; ++j) {
    int nb = w * 8 + j;
    int n  = nb * 16 + l16;
    int kb = 4 * q;
    uint4 v;
    v.x = lds[(kb + 0) * 516 + n];
    v.y = lds[(kb + 1) * 516 + n];
    v.z = lds[(kb + 2) * 516 + n];
    v.w = lds[(kb + 3) * 516 + n];
    outp[nb * 64 + l] = v;                     // 16B/lane, lanes consecutive
  }
}

// ---------------------------------------------------------------------------
// Fused MLP v10 = v9 (best: 179.6us, MfmaUtil 47%) with ONE change:
// EXPERT-PER-XCD-EPOCH block map. v9's map put all 4 of an XCD's experts
// co-resident (5.4MB > 4MB L2 -> weight thrash; FETCH showed weights x2.4,
// L2-miss latency > B-prefetch depth -> the 53% stall). Now:
//   xcd = bid&7, k = bid>>3 (0..255): e = xcd*4 + (k>>6), m0 = (k&63)*64.
// Epoch = 64 blocks = exactly the XCD's 64 block slots, all ONE expert
// (1.34MB << 4MB L2): each weight chunk HBM-fetched once, L2-hit by the
// other 63 blocks. Acts (4.7MB, L3-resident) re-filled per epoch -- but in
// the block PROLOGUE, off the chunk-loop critical path.
// Everything else identical to v9 (fragment-major A, copy-free 2-chunk
// role-swap B dbuf, setprio around MFMA, same epilogues).
// ---------------------------------------------------------------------------
__global__ __launch_bounds__(512, 4) void mlp_kernel(
    const float* __restrict__ theta, const float* __restrict__ x,
    const short8* __restrict__ wcat, const short8* __restrict__ whf,
    const float* __restrict__ b1, const float* __restrict__ a1,
    const float* __restrict__ bh, const float* __restrict__ ah,
    const float* __restrict__ Wo, const float* __restrict__ bo,
    float* __restrict__ out) {
  __shared__ __align__(16) char smA[4 * 16 * 64 * 16];   // 65536 B
  const int tid = threadIdx.x;
  const int bid = blockIdx.x;
  const int xcd = bid & 7;
  const int kk  = bid >> 3;                       // per-XCD sequence 0..255
  const int e   = xcd * 4 + (kk >> 6);            // one expert per XCD-epoch
  const int m0  = (kk & 63) * BM;
  const int w   = tid >> 6, l = tid & 63, l16 = l & 15, quad = l >> 4;

  // ---- stage A0 = [theta | x] bf16, directly in fragment order ----
  // g: lane=g&63, mb=(g>>6)&3, kt=g>>8; row = mb*16+(lane&15),
  // k = kt*32 + (lane>>4)*8 .. +7  (kt==0 -> theta cols, else x cols).
  for (int g = tid; g < 9 * 256; g += 512) {
    int lane = g & 63, mb = (g >> 6) & 3, kt = g >> 8;
    int row  = m0 + mb * 16 + (lane & 15);
    int ks   = (lane >> 4) * 8;
    const float* src = (kt == 0)
                           ? (theta + (size_t)row * T_SZ + ks)
                           : (x + (size_t)row * X_SZ + (kt - 1) * 32 + ks);
    float4 a = *(const float4*)src;
    float4 b = *(const float4*)(src + 4);
    *(uint4*)(smA + mb * 16384 + kt * 1024 + lane * 16) =
        make_uint4(pk2(a.x, a.y), pk2(a.z, a.w), pk2(b.x, b.y), pk2(b.z, b.w));
  }
  __syncthreads();

  floatx4 acc[4][4];
  const int u0 = w * 256 + l;                     // weight unit index (nb=4w)
  const char* dsb0 = smA + l * 16;                // A-frag base (chunk 0)

  // GEMM over nkt K-chunks of 32. Runtime loop, 2 chunks/iter, bA/bB role
  // swap (no copies); af read fresh per chunk (plain form - fastest measured).
  auto gemm = [&](const short8* wbase, int nkt) {
#pragma unroll
    for (int m = 0; m < 4; ++m)
#pragma unroll
      for (int i = 0; i < 4; ++i) acc[m][i] = (floatx4)(0.f);
    short8 bA[4], bB[4];
    const short8* wu = wbase;                     // uniform -> SGPR base
#pragma unroll
    for (int i = 0; i < 4; ++i) bA[i] = wu[u0 + i * 64];   // chunk 0
    const char* dsb = dsb0;
    const int half = nkt >> 1;
#pragma unroll 1
    for (int j = 0; j < half; ++j) {
      // prefetch odd chunk 2j+1 (always valid inside loop)
      const short8* w1 = wu + 2048;
#pragma unroll
      for (int i = 0; i < 4; ++i) bB[i] = w1[u0 + i * 64];
      // chunk 2j with bA
      {
        short8 af[4];
#pragma unroll
        for (int m = 0; m < 4; ++m)
          af[m] = *(const short8*)(dsb + m * 16384);
        __builtin_amdgcn_s_setprio(1);
#pragma unroll
        for (int m = 0; m < 4; ++m)
#pragma unroll
          for (int i = 0; i < 4; ++i)
            acc[m][i] = __builtin_amdgcn_mfma_f32_16x16x32_bf16(
                af[m], bA[i], acc[m][i], 0, 0, 0);
        __builtin_amdgcn_s_setprio(0);
      }
      // prefetch chunk 2j+2 (clamped at layer end; uniform select -> SALU)
      const short8* w2 = (2 * j + 2 < nkt) ? wu + 4096 : wu;
#pragma unroll
      for (int i = 0; i < 4; ++i) bA[i] = w2[u0 + i * 64];
      // chunk 2j+1 with bB
      {
        short8 af[4];
#pragma unroll
        for (int m = 0; m < 4; ++m)
          af[m] = *(const short8*)(dsb + m * 16384 + 1024);
        __builtin_amdgcn_s_setprio(1);
#pragma unroll
        for (int m = 0; m < 4; ++m)
#pragma unroll
          for (int i = 0; i < 4; ++i)
            acc[m][i] = __builtin_amdgcn_mfma_f32_16x16x32_bf16(
                af[m], bB[i], acc[m][i], 0, 0, 0);
        __builtin_amdgcn_s_setprio(0);
      }
      wu += 4096;
      dsb += 2048;
    }
    if (nkt & 1) {                                // tail chunk nkt-1 (in bA)
      short8 af[4];
#pragma unroll
      for (int m = 0; m < 4; ++m)
        af[m] = *(const short8*)(dsb + m * 16384);
      __builtin_amdgcn_s_setprio(1);
#pragma unroll
      for (int m = 0; m < 4; ++m)
#pragma unroll
        for (int i = 0; i < 4; ++i)
          acc[m][i] = __builtin_amdgcn_mfma_f32_16x16x32_bf16(
              af[m], bA[i], acc[m][i], 0, 0, 0);
      __builtin_amdgcn_s_setprio(0);
    }
  };

  // bias + PReLU + bf16 pair-pack (shfl_xor 1) + write into fragment-major A.
  // Value (R = mb*16+quad*4+r, C = w*64+i*16+l16) -> unit mb'=mb,
  // kt' = w*2+(i>>1), lane' = (R&15) + ((i*2+(l16>>3))&3)*16,
  // byte-in-lane (l16&6)*2.
  auto epi_store = [&](const float* bias, const float* slope) {
    float bb[4], aa[4];
#pragma unroll
    for (int i = 0; i < 4; ++i) {
      int col = w * 64 + i * 16 + l16;
      bb[i] = bias[col];
      aa[i] = slope[col];
    }
    __syncthreads();   // everyone done READING A before we overwrite
#pragma unroll
    for (int mb = 0; mb < 4; ++mb) {
#pragma unroll
      for (int i = 0; i < 4; ++i) {
        unsigned dw[4];
#pragma unroll
        for (int r = 0; r < 4; ++r) {
          float v = acc[mb][i][r] + bb[i];
          v = v >= 0.f ? v : aa[i] * v;
          float o  = __shfl_xor(v, 1, 64);
          float lo = (l16 & 1) ? o : v;
          float hi = (l16 & 1) ? v : o;
          dw[r] = pk2(lo, hi);
        }
        int rbase = (l16 & 1) * 2;               // even lanes rows 0,1; odd 2,3
        int ktp   = w * 2 + (i >> 1);
        int lhi   = ((i * 2 + (l16 >> 3)) & 3) * 16;
        char* ubase = smA + mb * 16384 + ktp * 1024 + (l16 & 6) * 2;
#pragma unroll
        for (int rr = 0; rr < 2; ++rr) {
          int lane_p = (quad * 4 + rbase + rr) + lhi;
          *(unsigned*)(ubase + lane_p * 16) = dw[rbase + rr];
        }
      }
    }
    __syncthreads();
  };

  // ---- layer 1: K = 288 (9 chunks) ----
  gemm(wcat + (size_t)e * 9 * 2048, 9);
  epi_store(b1 + (size_t)e * H_SZ, a1 + (size_t)e * H_SZ);
  // ---- hidden layer 0: K = 512 (16 chunks) ----
  gemm(whf + (size_t)e * 16 * 2048, 16);
  epi_store(bh + (size_t)e * H_SZ, ah + (size_t)e * H_SZ);
  // ---- hidden layer 1 + fused output dot (fp32, no bf16 rounding) ----
  gemm(whf + (size_t)(E_SZ + e) * 16 * 2048, 16);
  {
    float bb[4], aa[4], wo[4];
#pragma unroll
    for (int i = 0; i < 4; ++i) {
      int col = w * 64 + i * 16 + l16;
      bb[i] = bh[(size_t)(E_SZ + e) * H_SZ + col];
      aa[i] = ah[(size_t)(E_SZ + e) * H_SZ + col];
      wo[i] = Wo[(size_t)e * H_SZ + col];
    }
    float ps[4][4];
#pragma unroll
    for (int m = 0; m < 4; ++m)
#pragma unroll
      for (int r = 0; r < 4; ++r) ps[m][r] = 0.f;
#pragma unroll
    for (int m = 0; m < 4; ++m)
#pragma unroll
      for (int i = 0; i < 4; ++i)
#pragma unroll
        for (int r = 0; r < 4; ++r) {
          float v = acc[m][i][r] + bb[i];
          v = v >= 0.f ? v : aa[i] * v;
          ps[m][r] += v * wo[i];
        }
    // reduce over the 16 lanes of each quad (cols within this wave's strip)
#pragma unroll
    for (int d = 1; d < 16; d <<= 1)
#pragma unroll
      for (int m = 0; m < 4; ++m)
#pragma unroll
        for (int r = 0; r < 4; ++r) ps[m][r] += __shfl_xor(ps[m][r], d, 64);
    __syncthreads();                 // done reading A; reuse its storage
    float* scratch = (float*)smA;    // [64 rows][8 col-strips]
    if (l16 == 0) {
#pragma unroll
      for (int m = 0; m < 4; ++m)
#pragma unroll
        for (int r = 0; r < 4; ++r)
          scratch[(m * 16 + quad * 4 + r) * 8 + w] = ps[m][r];
    }
    __syncthreads();
    if (tid < BM) {
      float s = 0.f;
#pragma unroll
      for (int ww = 0; ww < 8; ++ww) s += scratch[tid * 8 + ww];
      out[(size_t)(m0 + tid) * E_SZ + e] = s + bo[e];
    }
  }
}

// ---------------------------------------------------------------------------
extern "C" void kernel_launch(void* const* d_in, const int* in_sizes, int n_in,
                              void* d_out, int out_size, void* d_ws, size_t ws_size,
                              hipStream_t stream) {
  const float* theta = (const float*)d_in[0];
  const float* x     = (const float*)d_in[1];
  const int*   masks = (const int*)d_in[2];
  const float* W1t   = (const float*)d_in[3];
  const float* W1x   = (const float*)d_in[4];
  const float* b1    = (const float*)d_in[5];
  const float* a1    = (const float*)d_in[6];
  const float* Wh    = (const float*)d_in[7];
  const float* bh    = (const float*)d_in[8];
  const float* ah    = (const float*)d_in[9];
  const float* Wo    = (const float*)d_in[10];
  const float* bo    = (const float*)d_in[11];
  float* out = (float*)d_out;

  // ws layout: [0, 9.4MB) layer-1 frags; [9.4MB, 43MB) hidden frags.
  uint4* wcat = (uint4*)d_ws;
  uint4* whf  = (uint4*)((char*)d_ws + (size_t)E_SZ * 9 * 2048 * 16);

  // 288 layer-1 chunks + 1024 hidden chunks, one block each
  prep_kernel<<<1312, 256, 0, stream>>>(W1t, W1x, masks, Wh, wcat, whf);
  // 2048 blocks: 64 m-tiles x 32 experts, 512 threads, 2 blocks/CU
  mlp_kernel<<<2048, 512, 0, stream>>>(theta, x, (const short8*)wcat,
                                       (const short8*)whf, b1, a1, bh, ah, Wo,
                                       bo, out);
}

// Round 13
// 303.418 us; speedup vs baseline: 1.1939x; 1.0054x over previous
//
#include <hip/hip_runtime.h>
#include <stdint.h>

// Problem constants (from reference): B,T,X,E,H,L = 4096,32,256,32,512,2
#define B_SZ 4096
#define T_SZ 32
#define X_SZ 256
#define E_SZ 32
#define H_SZ 512
#define BM   64      // batch rows per block; 2 blocks/CU (independent phases)

typedef __attribute__((ext_vector_type(8))) short  short8;   // 8 bf16 = 4 VGPR
typedef __attribute__((ext_vector_type(4))) float  floatx4;

// v_cvt_pk_bf16_f32: D[15:0]=bf16(a), D[31:16]=bf16(b), RNE (gfx950 HW instr)
__device__ __forceinline__ unsigned pk2(float a, float b) {
  unsigned r;
  asm("v_cvt_pk_bf16_f32 %0, %1, %2" : "=v"(r) : "v"(a), "v"(b));
  return r;
}

// ---------------------------------------------------------------------------
// Prep: fp32 weights -> bf16 MFMA B-fragments via LDS transpose. (unchanged)
// One block per chunk (32 k x 512 n). 1312 chunks total:
//   c in [0,288):    layer-1, c = e*9+kt. kt==0 -> masked W1t rows 0..31;
//                    kt>=1 -> W1x rows (kt-1)*32 .. +31.   out: wcat.
//   c in [288,1312): hidden, c-288 = (layer*32+e)*16 + kt. out: whf.
// Unit layout (contract with mlp_kernel): u = nb*64 + l,
//   n = nb*16 + (l&15), local k0 = (l>>4)*8, dword p covers k = k0+2p, k0+2p+1.
// ---------------------------------------------------------------------------
__global__ __launch_bounds__(256) void prep_kernel(
    const float* __restrict__ W1t, const float* __restrict__ W1x,
    const int* __restrict__ masks, const float* __restrict__ Wh,
    uint4* __restrict__ wcat, uint4* __restrict__ whf) {
  __shared__ unsigned lds[16 * 516];           // 33 KB
  const int c = blockIdx.x;
  const int t = threadIdx.x;

  const float* base;                           // row 0 of this chunk's 32 rows
  bool needMask = false;
  int e1 = 0;
  if (c >= 288) {
    int cc = c - 288;
    int le = cc >> 4, kt = cc & 15;            // le = layer*32 + e
    base = Wh + ((size_t)le * H_SZ + kt * 32) * H_SZ;
  } else {
    int e = c / 9, kt = c - e * 9;
    e1 = e;
    if (kt == 0) { base = W1t + (size_t)e * T_SZ * H_SZ; needMask = true; }
    else          base = W1x + ((size_t)e * X_SZ + (kt - 1) * 32) * H_SZ;
  }

#pragma unroll
  for (int i = 0; i < 8; ++i) {
    int g  = i * 256 + t;
    int k2 = g >> 7, np = g & 127;             // k2: wave-uniform
    const float* r0 = base + (size_t)(2 * k2) * H_SZ + np * 4;
    float4 a = *(const float4*)r0;
    float4 b = *(const float4*)(r0 + H_SZ);
    if (needMask) {
      float s0 = (float)masks[e1 * T_SZ + 2 * k2];
      float s1 = (float)masks[e1 * T_SZ + 2 * k2 + 1];
      a.x *= s0; a.y *= s0; a.z *= s0; a.w *= s0;
      b.x *= s1; b.y *= s1; b.z *= s1; b.w *= s1;
    }
    *(uint4*)&lds[k2 * 516 + np * 4] =
        make_uint4(pk2(a.x, b.x), pk2(a.y, b.y), pk2(a.z, b.z), pk2(a.w, b.w));
  }
  __syncthreads();

  uint4* outp = (c < 288) ? (wcat + (size_t)c * 2048)
                          : (whf + (size_t)(c - 288) * 2048);
  const int w = t >> 6, l = t & 63, q = l >> 4, l16 = l & 15;
#pragma unroll
  for (int j = 0; j < 8; ++j) {
    int nb = w * 8 + j;
    int n  = nb * 16 + l16;
    int kb = 4 * q;
    uint4 v;
    v.x = lds[(kb + 0) * 516 + n];
    v.y = lds[(kb + 1) * 516 + n];
    v.z = lds[(kb + 2) * 516 + n];
    v.w = lds[(kb + 3) * 516 + n];
    outp[nb * 64 + l] = v;                     // 16B/lane, lanes consecutive
  }
}

// ---------------------------------------------------------------------------
// Fused MLP v11 = v10 (177.2us, MfmaUtil 48.9%) with ONE change:
// TIME-STAGGER of co-resident blocks. Evidence trail: wall/chunk-round = SUM
// of pipes (matrix 1243 + vmem ~1024 + LDS ~770 ~= 2591 measured) in every
// variant; capacity of each pipe is under its ceiling; L2-residency of
// weights (v10) didn't move util -> the two co-resident blocks are
// PHASE-LOCKED (identical code, same start, same data sequence): both hit
// load-wait windows together (matrix idle) and MFMA bursts together (vmem
// idle). Fix: odd blocks sleep ~1280cy (half a chunk-round) once, after
// A-staging -> permanent ~180-degree anti-phase; one block's MFMA covers the
// other's loads. (R1's K-rotation "stagger" changed WHICH chunk, not WHEN --
// it could not test this.) Everything else identical to v10.
// ---------------------------------------------------------------------------
__global__ __launch_bounds__(512, 4) void mlp_kernel(
    const float* __restrict__ theta, const float* __restrict__ x,
    const short8* __restrict__ wcat, const short8* __restrict__ whf,
    const float* __restrict__ b1, const float* __restrict__ a1,
    const float* __restrict__ bh, const float* __restrict__ ah,
    const float* __restrict__ Wo, const float* __restrict__ bo,
    float* __restrict__ out) {
  __shared__ __align__(16) char smA[4 * 16 * 64 * 16];   // 65536 B
  const int tid = threadIdx.x;
  const int bid = blockIdx.x;
  const int xcd = bid & 7;
  const int kk  = bid >> 3;                       // per-XCD sequence 0..255
  const int e   = xcd * 4 + (kk >> 6);            // one expert per XCD-epoch
  const int m0  = (kk & 63) * BM;
  const int w   = tid >> 6, l = tid & 63, l16 = l & 15, quad = l >> 4;

  // ---- stage A0 = [theta | x] bf16, directly in fragment order ----
  // g: lane=g&63, mb=(g>>6)&3, kt=g>>8; row = mb*16+(lane&15),
  // k = kt*32 + (lane>>4)*8 .. +7  (kt==0 -> theta cols, else x cols).
  for (int g = tid; g < 9 * 256; g += 512) {
    int lane = g & 63, mb = (g >> 6) & 3, kt = g >> 8;
    int row  = m0 + mb * 16 + (lane & 15);
    int ks   = (lane >> 4) * 8;
    const float* src = (kt == 0)
                           ? (theta + (size_t)row * T_SZ + ks)
                           : (x + (size_t)row * X_SZ + (kt - 1) * 32 + ks);
    float4 a = *(const float4*)src;
    float4 b = *(const float4*)(src + 4);
    *(uint4*)(smA + mb * 16384 + kt * 1024 + lane * 16) =
        make_uint4(pk2(a.x, a.y), pk2(a.z, a.w), pk2(b.x, b.y), pk2(b.z, b.w));
  }
  __syncthreads();

  // Anti-phase: odd blocks delay ~1280cy (~half a chunk-round) once.
  if (kk & 1) __builtin_amdgcn_s_sleep(20);

  floatx4 acc[4][4];
  const int u0 = w * 256 + l;                     // weight unit index (nb=4w)
  const char* dsb0 = smA + l * 16;                // A-frag base (chunk 0)

  // GEMM over nkt K-chunks of 32. Runtime loop, 2 chunks/iter, bA/bB role
  // swap (no copies); af read fresh per chunk (plain form - fastest measured).
  auto gemm = [&](const short8* wbase, int nkt) {
#pragma unroll
    for (int m = 0; m < 4; ++m)
#pragma unroll
      for (int i = 0; i < 4; ++i) acc[m][i] = (floatx4)(0.f);
    short8 bA[4], bB[4];
    const short8* wu = wbase;                     // uniform -> SGPR base
#pragma unroll
    for (int i = 0; i < 4; ++i) bA[i] = wu[u0 + i * 64];   // chunk 0
    const char* dsb = dsb0;
    const int half = nkt >> 1;
#pragma unroll 1
    for (int j = 0; j < half; ++j) {
      // prefetch odd chunk 2j+1 (always valid inside loop)
      const short8* w1 = wu + 2048;
#pragma unroll
      for (int i = 0; i < 4; ++i) bB[i] = w1[u0 + i * 64];
      // chunk 2j with bA
      {
        short8 af[4];
#pragma unroll
        for (int m = 0; m < 4; ++m)
          af[m] = *(const short8*)(dsb + m * 16384);
        __builtin_amdgcn_s_setprio(1);
#pragma unroll
        for (int m = 0; m < 4; ++m)
#pragma unroll
          for (int i = 0; i < 4; ++i)
            acc[m][i] = __builtin_amdgcn_mfma_f32_16x16x32_bf16(
                af[m], bA[i], acc[m][i], 0, 0, 0);
        __builtin_amdgcn_s_setprio(0);
      }
      // prefetch chunk 2j+2 (clamped at layer end; uniform select -> SALU)
      const short8* w2 = (2 * j + 2 < nkt) ? wu + 4096 : wu;
#pragma unroll
      for (int i = 0; i < 4; ++i) bA[i] = w2[u0 + i * 64];
      // chunk 2j+1 with bB
      {
        short8 af[4];
#pragma unroll
        for (int m = 0; m < 4; ++m)
          af[m] = *(const short8*)(dsb + m * 16384 + 1024);
        __builtin_amdgcn_s_setprio(1);
#pragma unroll
        for (int m = 0; m < 4; ++m)
#pragma unroll
          for (int i = 0; i < 4; ++i)
            acc[m][i] = __builtin_amdgcn_mfma_f32_16x16x32_bf16(
                af[m], bB[i], acc[m][i], 0, 0, 0);
        __builtin_amdgcn_s_setprio(0);
      }
      wu += 4096;
      dsb += 2048;
    }
    if (nkt & 1) {                                // tail chunk nkt-1 (in bA)
      short8 af[4];
#pragma unroll
      for (int m = 0; m < 4; ++m)
        af[m] = *(const short8*)(dsb + m * 16384);
      __builtin_amdgcn_s_setprio(1);
#pragma unroll
      for (int m = 0; m < 4; ++m)
#pragma unroll
        for (int i = 0; i < 4; ++i)
          acc[m][i] = __builtin_amdgcn_mfma_f32_16x16x32_bf16(
              af[m], bA[i], acc[m][i], 0, 0, 0);
      __builtin_amdgcn_s_setprio(0);
    }
  };

  // bias + PReLU + bf16 pair-pack (shfl_xor 1) + write into fragment-major A.
  // Value (R = mb*16+quad*4+r, C = w*64+i*16+l16) -> unit mb'=mb,
  // kt' = w*2+(i>>1), lane' = (R&15) + ((i*2+(l16>>3))&3)*16,
  // byte-in-lane (l16&6)*2.
  auto epi_store = [&](const float* bias, const float* slope) {
    float bb[4], aa[4];
#pragma unroll
    for (int i = 0; i < 4; ++i) {
      int col = w * 64 + i * 16 + l16;
      bb[i] = bias[col];
      aa[i] = slope[col];
    }
    __syncthreads();   // everyone done READING A before we overwrite
#pragma unroll
    for (int mb = 0; mb < 4; ++mb) {
#pragma unroll
      for (int i = 0; i < 4; ++i) {
        unsigned dw[4];
#pragma unroll
        for (int r = 0; r < 4; ++r) {
          float v = acc[mb][i][r] + bb[i];
          v = v >= 0.f ? v : aa[i] * v;
          float o  = __shfl_xor(v, 1, 64);
          float lo = (l16 & 1) ? o : v;
          float hi = (l16 & 1) ? v : o;
          dw[r] = pk2(lo, hi);
        }
        int rbase = (l16 & 1) * 2;               // even lanes rows 0,1; odd 2,3
        int ktp   = w * 2 + (i >> 1);
        int lhi   = ((i * 2 + (l16 >> 3)) & 3) * 16;
        char* ubase = smA + mb * 16384 + ktp * 1024 + (l16 & 6) * 2;
#pragma unroll
        for (int rr = 0; rr < 2; ++rr) {
          int lane_p = (quad * 4 + rbase + rr) + lhi;
          *(unsigned*)(ubase + lane_p * 16) = dw[rbase + rr];
        }
      }
    }
    __syncthreads();
  };

  // ---- layer 1: K = 288 (9 chunks) ----
  gemm(wcat + (size_t)e * 9 * 2048, 9);
  epi_store(b1 + (size_t)e * H_SZ, a1 + (size_t)e * H_SZ);
  // ---- hidden layer 0: K = 512 (16 chunks) ----
  gemm(whf + (size_t)e * 16 * 2048, 16);
  epi_store(bh + (size_t)e * H_SZ, ah + (size_t)e * H_SZ);
  // ---- hidden layer 1 + fused output dot (fp32, no bf16 rounding) ----
  gemm(whf + (size_t)(E_SZ + e) * 16 * 2048, 16);
  {
    float bb[4], aa[4], wo[4];
#pragma unroll
    for (int i = 0; i < 4; ++i) {
      int col = w * 64 + i * 16 + l16;
      bb[i] = bh[(size_t)(E_SZ + e) * H_SZ + col];
      aa[i] = ah[(size_t)(E_SZ + e) * H_SZ + col];
      wo[i] = Wo[(size_t)e * H_SZ + col];
    }
    float ps[4][4];
#pragma unroll
    for (int m = 0; m < 4; ++m)
#pragma unroll
      for (int r = 0; r < 4; ++r) ps[m][r] = 0.f;
#pragma unroll
    for (int m = 0; m < 4; ++m)
#pragma unroll
      for (int i = 0; i < 4; ++i)
#pragma unroll
        for (int r = 0; r < 4; ++r) {
          float v = acc[m][i][r] + bb[i];
          v = v >= 0.f ? v : aa[i] * v;
          ps[m][r] += v * wo[i];
        }
    // reduce over the 16 lanes of each quad (cols within this wave's strip)
#pragma unroll
    for (int d = 1; d < 16; d <<= 1)
#pragma unroll
      for (int m = 0; m < 4; ++m)
#pragma unroll
        for (int r = 0; r < 4; ++r) ps[m][r] += __shfl_xor(ps[m][r], d, 64);
    __syncthreads();                 // done reading A; reuse its storage
    float* scratch = (float*)smA;    // [64 rows][8 col-strips]
    if (l16 == 0) {
#pragma unroll
      for (int m = 0; m < 4; ++m)
#pragma unroll
        for (int r = 0; r < 4; ++r)
          scratch[(m * 16 + quad * 4 + r) * 8 + w] = ps[m][r];
    }
    __syncthreads();
    if (tid < BM) {
      float s = 0.f;
#pragma unroll
      for (int ww = 0; ww < 8; ++ww) s += scratch[tid * 8 + ww];
      out[(size_t)(m0 + tid) * E_SZ + e] = s + bo[e];
    }
  }
}

// ---------------------------------------------------------------------------
extern "C" void kernel_launch(void* const* d_in, const int* in_sizes, int n_in,
                              void* d_out, int out_size, void* d_ws, size_t ws_size,
                              hipStream_t stream) {
  const float* theta = (const float*)d_in[0];
  const float* x     = (const float*)d_in[1];
  const int*   masks = (const int*)d_in[2];
  const float* W1t   = (const float*)d_in[3];
  const float* W1x   = (const float*)d_in[4];
  const float* b1    = (const float*)d_in[5];
  const float* a1    = (const float*)d_in[6];
  const float* Wh    = (const float*)d_in[7];
  const float* bh    = (const float*)d_in[8];
  const float* ah    = (const float*)d_in[9];
  const float* Wo    = (const float*)d_in[10];
  const float* bo    = (const float*)d_in[11];
  float* out = (float*)d_out;

  // ws layout: [0, 9.4MB) layer-1 frags; [9.4MB, 43MB) hidden frags.
  uint4* wcat = (uint4*)d_ws;
  uint4* whf  = (uint4*)((char*)d_ws + (size_t)E_SZ * 9 * 2048 * 16);

  // 288 layer-1 chunks + 1024 hidden chunks, one block each
  prep_kernel<<<1312, 256, 0, stream>>>(W1t, W1x, masks, Wh, wcat, whf);
  // 2048 blocks: 64 m-tiles x 32 experts, 512 threads, 2 blocks/CU
  mlp_kernel<<<2048, 512, 0, stream>>>(theta, x, (const short8*)wcat,
                                       (const short8*)whf, b1, a1, bh, ah, Wo,
                                       bo, out);
}